// Round 5
// baseline (275.568 us; speedup 1.0000x reference)
//
#include <hip/hip_runtime.h>
#include <hip/hip_bf16.h>

// ---------------------------------------------------------------------------
// R4: fp8 e4m3 KV to halve the attention gather traffic.
//   R3 evidence: FETCH unchanged 144MB, BW 2.5->3.1TB/s on 2x MLP -> L3
//   random-gather throughput ceiling; cut bytes/edge 1KB -> 512B.
//   K,V stored interleaved as fp8 [N][512]B; GEMM epilogue converts;
//   attn decodes with v_cvt_pk_f32_fp8. q/r bf16, accum f32.
// ---------------------------------------------------------------------------

#define DEVFN static __device__ __forceinline__

typedef __attribute__((ext_vector_type(4))) float f32x4;
typedef __attribute__((ext_vector_type(2))) float f32x2;
typedef __attribute__((ext_vector_type(8))) short bf16x8;

DEVFN float bfu2f(unsigned short u) {
    union { unsigned int i; float f; } t; t.i = ((unsigned)u) << 16; return t.f;
}
DEVFN float4 ldb4(const __hip_bfloat16* p) {
    ushort4 u = *reinterpret_cast<const ushort4*>(p);
    return make_float4(bfu2f(u.x), bfu2f(u.y), bfu2f(u.z), bfu2f(u.w));
}
DEVFN unsigned short f2bu(float f) {
    __hip_bfloat16 b = __float2bfloat16(f);
    return __builtin_bit_cast(unsigned short, b);
}
DEVFN void stb4(__hip_bfloat16* p, float4 v) {
    ushort4 u;
    u.x = f2bu(v.x); u.y = f2bu(v.y); u.z = f2bu(v.z); u.w = f2bu(v.w);
    *reinterpret_cast<ushort4*>(p) = u;
}
DEVFN float4 f8x4_to_f4(unsigned u) {
    const f32x2 lo = __builtin_amdgcn_cvt_pk_f32_fp8((int)u, false);
    const f32x2 hi = __builtin_amdgcn_cvt_pk_f32_fp8((int)u, true);
    return make_float4(lo.x, lo.y, hi.x, hi.y);
}

// --------------------------- converts ---------------------------------------
__global__ __launch_bounds__(256)
void f2b_kernel(const float* __restrict__ in, __hip_bfloat16* __restrict__ out, int n4)
{
    const int i = blockIdx.x * 256 + threadIdx.x;
    if (i >= n4) return;
    const float4 v = *reinterpret_cast<const float4*>(in + (size_t)i * 4);
    stb4(out + (size_t)i * 4, v);
}

// transpose+convert weights: W[k][c] f32 -> Wt[z][c][k] bf16
__global__ __launch_bounds__(256)
void wconv_kernel(const float* __restrict__ W0, const float* __restrict__ W1,
                  const float* __restrict__ W2, const float* __restrict__ W3,
                  const float* __restrict__ W4, const float* __restrict__ W5,
                  const float* __restrict__ W6, const float* __restrict__ W7,
                  __hip_bfloat16* __restrict__ Wt)
{
    const float* W;
    switch (blockIdx.y) {
        case 0: W = W0; break; case 1: W = W1; break;
        case 2: W = W2; break; case 3: W = W3; break;
        case 4: W = W4; break; case 5: W = W5; break;
        case 6: W = W6; break; default: W = W7; break;
    }
    const int k = blockIdx.x;      // 0..255
    const int c = threadIdx.x;     // 0..255
    Wt[(size_t)blockIdx.y * 65536 + (size_t)c * 256 + k] =
        __float2bfloat16(W[(size_t)k * 256 + c]);
}

// ------------------------- GEMM: O[z] = A @ W[z] + b[z] ---------------------
// Per-output: byte-granular base pointer, row stride (elements), fp8 flag.
#define SWZ(r, kb) ((r) * 256 + ((kb) ^ (((r) & 7) << 4)))

__global__ __launch_bounds__(256)
void gemm_mfma_kernel(const __hip_bfloat16* __restrict__ A, int M,
                      const __hip_bfloat16* __restrict__ Wt,
                      const float* __restrict__ b0, const float* __restrict__ b1,
                      const float* __restrict__ b2, const float* __restrict__ b3,
                      void* __restrict__ O0, void* __restrict__ O1,
                      void* __restrict__ O2, void* __restrict__ O3,
                      int s0, int s1, int s2, int s3,
                      int f0, int f1, int f2, int f3)
{
    const int z = blockIdx.z;
    const float* bias; void* O; int rs, isf8;
    switch (z) {
        case 0:  bias = b0; O = O0; rs = s0; isf8 = f0; break;
        case 1:  bias = b1; O = O1; rs = s1; isf8 = f1; break;
        case 2:  bias = b2; O = O2; rs = s2; isf8 = f2; break;
        default: bias = b3; O = O3; rs = s3; isf8 = f3; break;
    }
    const __hip_bfloat16* Wz = Wt + (size_t)z * 65536;

    __shared__ char As[128 * 256];
    __shared__ char Bs[128 * 256];

    const int tid  = threadIdx.x;
    const int row0 = blockIdx.x * 128;
    const int col0 = blockIdx.y * 128;
    const int wid  = tid >> 6, lane = tid & 63;
    const int wr   = wid >> 1, wc = wid & 1;
    const int lrow = lane & 15, kg = lane >> 4;

    const int chunk = tid & 15;
    const int rsub  = tid >> 4;

    f32x4 acc[4][4] = {};

    for (int k0 = 0; k0 < 256; k0 += 128) {
        #pragma unroll
        for (int p = 0; p < 8; ++p) {
            const int r  = p * 16 + rsub;
            const int gr = row0 + r;
            ulonglong2 av = {0ull, 0ull};
            if (gr < M)
                av = *reinterpret_cast<const ulonglong2*>(A + (size_t)gr * 256 + k0 + chunk * 8);
            *reinterpret_cast<ulonglong2*>(As + SWZ(r, chunk * 16)) = av;

            const ulonglong2 bv = *reinterpret_cast<const ulonglong2*>(
                Wz + (size_t)(col0 + r) * 256 + k0 + chunk * 8);
            *reinterpret_cast<ulonglong2*>(Bs + SWZ(r, chunk * 16)) = bv;
        }
        __syncthreads();

        #pragma unroll
        for (int kk = 0; kk < 128; kk += 32) {
            const int kbyte = kk * 2 + kg * 16;
            bf16x8 af[4], bfr[4];
            #pragma unroll
            for (int m = 0; m < 4; ++m) {
                const int r = wr * 64 + m * 16 + lrow;
                af[m] = *reinterpret_cast<const bf16x8*>(As + SWZ(r, kbyte));
            }
            #pragma unroll
            for (int n = 0; n < 4; ++n) {
                const int c = wc * 64 + n * 16 + lrow;
                bfr[n] = *reinterpret_cast<const bf16x8*>(Bs + SWZ(c, kbyte));
            }
            #pragma unroll
            for (int m = 0; m < 4; ++m)
                #pragma unroll
                for (int n = 0; n < 4; ++n)
                    acc[m][n] = __builtin_amdgcn_mfma_f32_16x16x32_bf16(
                        af[m], bfr[n], acc[m][n], 0, 0, 0);
        }
        __syncthreads();
    }

    #pragma unroll
    for (int m = 0; m < 4; ++m) {
        #pragma unroll
        for (int j = 0; j < 4; ++j) {
            const int grow = row0 + wr * 64 + m * 16 + kg * 4 + j;
            if (grow >= M) continue;
            #pragma unroll
            for (int n = 0; n < 4; ++n) {
                const int gcol = col0 + wc * 64 + n * 16 + lrow;
                const float v = acc[m][n][j] + bias[gcol];
                if (isf8) {
                    const int pk = __builtin_amdgcn_cvt_pk_fp8_f32(v, v, 0, false);
                    ((unsigned char*)O)[(size_t)grow * rs + gcol] = (unsigned char)(pk & 0xFF);
                } else {
                    ((__hip_bfloat16*)O)[(size_t)grow * rs + gcol] = __float2bfloat16(v);
                }
            }
        }
    }
}

// ------------------------------ CSR build ----------------------------------
__global__ __launch_bounds__(256)
void hist_kernel(const int* __restrict__ ei, int E, int* __restrict__ deg)
{
    const int e = blockIdx.x * 256 + threadIdx.x;
    if (e < E) atomicAdd(&deg[ei[E + e]], 1);
}

__global__ __launch_bounds__(256)
void gcount_kernel(const int* __restrict__ batch, int N, int* __restrict__ gcount)
{
    __shared__ int h[16];
    if (threadIdx.x < 16) h[threadIdx.x] = 0;
    __syncthreads();
    const int n = blockIdx.x * 256 + threadIdx.x;
    if (n < N) atomicAdd(&h[batch[n]], 1);
    __syncthreads();
    if (threadIdx.x < 16 && h[threadIdx.x] != 0)
        atomicAdd(&gcount[threadIdx.x], h[threadIdx.x]);
}

__global__ __launch_bounds__(64)
void gstart_kernel(const int* __restrict__ gcount, int* __restrict__ gstart)
{
    if (threadIdx.x == 0) {
        int o = 0;
        for (int g = 0; g < 16; ++g) { gstart[g] = o; o += gcount[g]; }
        gstart[16] = o;
    }
}

__global__ __launch_bounds__(1024)
void scan_kernel(const int* __restrict__ deg, int* __restrict__ row_start, int n)
{
    __shared__ int wsum[16];
    __shared__ int wincl[16];
    const int tid  = threadIdx.x;
    const int w    = tid >> 6;
    const int lane = tid & 63;
    if (tid == 0) row_start[0] = 0;
    int offset = 0;
    for (int base = 0; base < n; base += 1024) {
        const int idx = base + tid;
        int s = (idx < n) ? deg[idx] : 0;
        #pragma unroll
        for (int d = 1; d < 64; d <<= 1) {
            const int t = __shfl_up(s, d, 64);
            if (lane >= d) s += t;
        }
        if (lane == 63) wsum[w] = s;
        __syncthreads();
        if (tid < 16) {
            int si = wsum[tid];
            #pragma unroll
            for (int d = 1; d < 16; d <<= 1) {
                const int u = __shfl_up(si, d, 64);
                if (tid >= d) si += u;
            }
            wincl[tid] = si;
        }
        __syncthreads();
        const int woff = (w > 0) ? wincl[w - 1] : 0;
        if (idx < n) row_start[idx + 1] = offset + woff + s;
        offset += wincl[15];
        __syncthreads();
    }
}

__global__ __launch_bounds__(256)
void fill_kernel(const int* __restrict__ ei, int E,
                 const int* __restrict__ row_start,
                 int* __restrict__ cursor, int* __restrict__ csr_src)
{
    const int e = blockIdx.x * 256 + threadIdx.x;
    if (e >= E) return;
    const int s = ei[e];
    const int d = ei[E + e];
    const int pos = atomicAdd(&cursor[d], 1);
    csr_src[row_start[d] + pos] = s;
}

// --------------------- fused attention + gate + layernorm ------------------
// 512 threads = 8 waves = 4 nodes x 2 waves; 2-deep unroll = 4 gather chains
// per node. KV is fp8 [N][512] bytes (K | V). Decode via v_cvt_pk_f32_fp8.
template <int HL, bool RELU, bool OUTB>
__global__ __launch_bounds__(512)
void attn_kernel(const __hip_bfloat16* __restrict__ Q,
                 const unsigned char* __restrict__ KV,
                 const __hip_bfloat16* __restrict__ R,
                 const float* __restrict__ Wb, const float* __restrict__ lng,
                 const float* __restrict__ lnb,
                 const int* __restrict__ row_start, const int* __restrict__ csr_src,
                 __hip_bfloat16* __restrict__ outb, float* __restrict__ outf,
                 int N, float scale)
{
    __shared__ float4 sAcc[4][64];
    __shared__ float  sSum[4][64];

    const int w    = threadIdx.x >> 6;     // 0..7
    const int lane = threadIdx.x & 63;
    const int slot = w >> 1;               // 0..3
    const int half = w & 1;
    const int node = blockIdx.x * 4 + slot;
    const bool active = node < N;

    const int d4 = lane * 4;
    float4 q4 = make_float4(0.f, 0.f, 0.f, 0.f);
    int beg = 0, end = 0;
    if (active) {
        q4  = ldb4(Q + (size_t)node * 256 + d4);
        beg = row_start[node];
        end = row_start[node + 1];
    }

    float4 acc0 = make_float4(0.f, 0.f, 0.f, 0.f);
    float4 acc1 = make_float4(0.f, 0.f, 0.f, 0.f);
    float  ssum0 = 0.f, ssum1 = 0.f;

    int i = beg + half;
    for (; i + 2 < end; i += 4) {
        const int sa = csr_src[i];
        const int sb = csr_src[i + 2];
        const unsigned* pa = reinterpret_cast<const unsigned*>(KV + (size_t)sa * 512 + d4);
        const unsigned* pb = reinterpret_cast<const unsigned*>(KV + (size_t)sb * 512 + d4);
        const unsigned kua = pa[0];
        const unsigned vua = pa[64];
        const unsigned kub = pb[0];
        const unsigned vub = pb[64];
        const float4 ka = f8x4_to_f4(kua);
        const float4 va = f8x4_to_f4(vua);
        const float4 kb = f8x4_to_f4(kub);
        const float4 vb = f8x4_to_f4(vub);
        float pa_ = q4.x * ka.x + q4.y * ka.y + q4.z * ka.z + q4.w * ka.w;
        float pb_ = q4.x * kb.x + q4.y * kb.y + q4.z * kb.z + q4.w * kb.w;
        #pragma unroll
        for (int m = 1; m < HL; m <<= 1) {
            pa_ += __shfl_xor(pa_, m, 64);
            pb_ += __shfl_xor(pb_, m, 64);
        }
        const float aa = __expf(pa_ * scale);
        const float ab = __expf(pb_ * scale);
        ssum0 += aa; ssum1 += ab;
        acc0.x = fmaf(aa, va.x, acc0.x); acc0.y = fmaf(aa, va.y, acc0.y);
        acc0.z = fmaf(aa, va.z, acc0.z); acc0.w = fmaf(aa, va.w, acc0.w);
        acc1.x = fmaf(ab, vb.x, acc1.x); acc1.y = fmaf(ab, vb.y, acc1.y);
        acc1.z = fmaf(ab, vb.z, acc1.z); acc1.w = fmaf(ab, vb.w, acc1.w);
    }
    if (i < end) {
        const int sa = csr_src[i];
        const unsigned* pa = reinterpret_cast<const unsigned*>(KV + (size_t)sa * 512 + d4);
        const unsigned kua = pa[0];
        const unsigned vua = pa[64];
        const float4 ka = f8x4_to_f4(kua);
        const float4 va = f8x4_to_f4(vua);
        float pa_ = q4.x * ka.x + q4.y * ka.y + q4.z * ka.z + q4.w * ka.w;
        #pragma unroll
        for (int m = 1; m < HL; m <<= 1) pa_ += __shfl_xor(pa_, m, 64);
        const float aa = __expf(pa_ * scale);
        ssum0 += aa;
        acc0.x = fmaf(aa, va.x, acc0.x); acc0.y = fmaf(aa, va.y, acc0.y);
        acc0.z = fmaf(aa, va.z, acc0.z); acc0.w = fmaf(aa, va.w, acc0.w);
    }

    float4 acc = make_float4(acc0.x + acc1.x, acc0.y + acc1.y,
                             acc0.z + acc1.z, acc0.w + acc1.w);
    float ssum = ssum0 + ssum1;

    if (half == 1) {
        sAcc[slot][lane] = acc;
        sSum[slot][lane] = ssum;
    }
    __syncthreads();
    if (half == 1 || !active) return;

    const float4 oa = sAcc[slot][lane];
    acc.x += oa.x; acc.y += oa.y; acc.z += oa.z; acc.w += oa.w;
    ssum += sSum[slot][lane];

    float4 o4 = make_float4(0.f, 0.f, 0.f, 0.f);
    if (ssum > 0.f) {
        const float is = 1.f / ssum;
        o4.x = acc.x * is; o4.y = acc.y * is; o4.z = acc.z * is; o4.w = acc.w * is;
    }

    const float4 r4  = ldb4(R + (size_t)node * 256 + d4);
    const float4 wb0 = *reinterpret_cast<const float4*>(Wb + d4);
    const float4 wb1 = *reinterpret_cast<const float4*>(Wb + 256 + d4);
    const float4 wb2 = *reinterpret_cast<const float4*>(Wb + 512 + d4);
    float z = o4.x * wb0.x + o4.y * wb0.y + o4.z * wb0.z + o4.w * wb0.w
            + r4.x * wb1.x + r4.y * wb1.y + r4.z * wb1.z + r4.w * wb1.w
            + (o4.x - r4.x) * wb2.x + (o4.y - r4.y) * wb2.y
            + (o4.z - r4.z) * wb2.z + (o4.w - r4.w) * wb2.w;
    #pragma unroll
    for (int m = 1; m < 64; m <<= 1) z += __shfl_xor(z, m, 64);
    const float g = 1.f / (1.f + __expf(-z));

    float4 h4;
    h4.x = g * r4.x + (1.f - g) * o4.x;
    h4.y = g * r4.y + (1.f - g) * o4.y;
    h4.z = g * r4.z + (1.f - g) * o4.z;
    h4.w = g * r4.w + (1.f - g) * o4.w;

    float s1 = h4.x + h4.y + h4.z + h4.w;
    float s2 = h4.x * h4.x + h4.y * h4.y + h4.z * h4.z + h4.w * h4.w;
    #pragma unroll
    for (int m = 1; m < 64; m <<= 1) {
        s1 += __shfl_xor(s1, m, 64);
        s2 += __shfl_xor(s2, m, 64);
    }
    const float mu  = s1 * (1.f / 256.f);
    const float var = s2 * (1.f / 256.f) - mu * mu;
    const float inv = rsqrtf(var + 1e-5f);

    const float4 ga = *reinterpret_cast<const float4*>(lng + d4);
    const float4 be = *reinterpret_cast<const float4*>(lnb + d4);
    h4.x = (h4.x - mu) * inv * ga.x + be.x;
    h4.y = (h4.y - mu) * inv * ga.y + be.y;
    h4.z = (h4.z - mu) * inv * ga.z + be.z;
    h4.w = (h4.w - mu) * inv * ga.w + be.w;

    if (RELU) {
        h4.x = fmaxf(h4.x, 0.f);
        h4.y = fmaxf(h4.y, 0.f);
        h4.z = fmaxf(h4.z, 0.f);
        h4.w = fmaxf(h4.w, 0.f);
    }

    if (OUTB) stb4(outb + (size_t)node * 256 + d4, h4);
    else      *reinterpret_cast<float4*>(outf + (size_t)node * 256 + d4) = h4;
}

// ------------------------------ mean pool (two-stage) ----------------------
__global__ __launch_bounds__(256)
void pool_partial_kernel(const float* __restrict__ h, const int* __restrict__ gstart,
                         float* __restrict__ partial)
{
    const int s    = blockIdx.x;
    const int g    = blockIdx.y;
    const int tid  = threadIdx.x;
    const int quad = tid & 63;
    const int sub  = tid >> 6;

    const int beg = gstart[g];
    const int cnt = gstart[g + 1] - beg;

    f32x4 acc = {0.f, 0.f, 0.f, 0.f};
    for (int i = s * 4 + sub; i < cnt; i += 64) {
        const f32x4 v = *reinterpret_cast<const f32x4*>(
            h + (size_t)(beg + i) * 256 + quad * 4);
        acc += v;
    }

    __shared__ f32x4 sh[4][64];
    sh[sub][quad] = acc;
    __syncthreads();
    if (sub == 0) {
        const f32x4 r = sh[0][quad] + sh[1][quad] + sh[2][quad] + sh[3][quad];
        *reinterpret_cast<f32x4*>(partial + ((size_t)(g * 16 + s) * 64 + quad) * 4) = r;
    }
}

__global__ __launch_bounds__(256)
void pool_final_kernel(const float* __restrict__ partial, const int* __restrict__ gcount,
                       float* __restrict__ out)
{
    const int g = blockIdx.x;
    const int d = threadIdx.x;
    float sum = 0.f;
    #pragma unroll
    for (int s = 0; s < 16; ++s)
        sum += partial[(size_t)(g * 16 + s) * 256 + d];
    out[(size_t)g * 256 + d] = sum / (float)max(gcount[g], 1);
}

// ------------------------------- launcher ----------------------------------
extern "C" void kernel_launch(void* const* d_in, const int* in_sizes, int n_in,
                              void* d_out, int out_size, void* d_ws, size_t ws_size,
                              hipStream_t stream)
{
    const float* x     = (const float*)d_in[0];
    const int*   ei    = (const int*)d_in[1];
    const int*   batch = (const int*)d_in[2];
    const float* Wq0 = (const float*)d_in[3];  const float* bq0 = (const float*)d_in[4];
    const float* Wk0 = (const float*)d_in[5];  const float* bk0 = (const float*)d_in[6];
    const float* Wv0 = (const float*)d_in[7];  const float* bv0 = (const float*)d_in[8];
    const float* Ws0 = (const float*)d_in[9];  const float* bs0 = (const float*)d_in[10];
    const float* Wb0 = (const float*)d_in[11];
    const float* g0  = (const float*)d_in[12]; const float* b0  = (const float*)d_in[13];
    const float* Wq1 = (const float*)d_in[14]; const float* bq1 = (const float*)d_in[15];
    const float* Wk1 = (const float*)d_in[16]; const float* bk1 = (const float*)d_in[17];
    const float* Wv1 = (const float*)d_in[18]; const float* bv1 = (const float*)d_in[19];
    const float* Ws1 = (const float*)d_in[20]; const float* bs1 = (const float*)d_in[21];
    const float* Wb1 = (const float*)d_in[22];
    const float* g1  = (const float*)d_in[23]; const float* b1  = (const float*)d_in[24];

    const int N = in_sizes[0] / 256;
    const int E = in_sizes[1] / 2;
    const int G = 16;
    const size_t NM = (size_t)N * 256;

    __hip_bfloat16* bws = (__hip_bfloat16*)d_ws;
    __hip_bfloat16* xb  = bws;
    __hip_bfloat16* qb  = xb  + NM;
    __hip_bfloat16* rb  = qb  + NM;
    __hip_bfloat16* h0b = rb  + NM;
    __hip_bfloat16* wt  = h0b + NM;               // 8 * 65536 bf16
    unsigned char* kvb  = (unsigned char*)(wt + 8 * 65536);   // [N][512] fp8
    float* h1f     = (float*)(kvb + (size_t)N * 512);
    float* partial = h1f + NM;                    // 16*16*256 f32
    int* deg       = (int*)(partial + 16 * 16 * 256);
    int* row_start = deg + N;
    int* cursor    = row_start + N + 1;
    int* gcount    = cursor + N;
    int* gstart    = gcount + G;                  // 17
    int* csr_src   = gstart + 17;

    const size_t zbytes = ((size_t)N + (N + 1) + N + G + 17) * sizeof(int);
    hipMemsetAsync(deg, 0, zbytes, stream);

    const int eb = (E + 255) / 256;
    const int nb = (N + 255) / 256;

    f2b_kernel<<<(int)((NM / 4 + 255) / 256), 256, 0, stream>>>(x, xb, (int)(NM / 4));
    wconv_kernel<<<dim3(256, 8), 256, 0, stream>>>(Wq0, Wk0, Wv0, Ws0,
                                                   Wq1, Wk1, Wv1, Ws1, wt);

    hist_kernel<<<eb, 256, 0, stream>>>(ei, E, deg);
    gcount_kernel<<<nb, 256, 0, stream>>>(batch, N, gcount);
    gstart_kernel<<<1, 64, 0, stream>>>(gcount, gstart);
    scan_kernel<<<1, 1024, 0, stream>>>(deg, row_start, N);
    fill_kernel<<<eb, 256, 0, stream>>>(ei, E, row_start, cursor, csr_src);

    const dim3 ggrid((N + 127) / 128, 2, 4);
    const int  agrid = (N + 3) / 4;

    // layer 0: q bf16, K fp8 (kv+0), V fp8 (kv+256), r bf16
    gemm_mfma_kernel<<<ggrid, 256, 0, stream>>>(xb, N, wt,
        bq0, bk0, bv0, bs0,
        qb, kvb, kvb + 256, rb,
        256, 512, 512, 256,
        0, 1, 1, 0);
    attn_kernel<16, true, true><<<agrid, 512, 0, stream>>>(
        qb, kvb, rb, Wb0, g0, b0, row_start, csr_src, h0b, nullptr, N, 0.125f);

    // layer 1
    gemm_mfma_kernel<<<ggrid, 256, 0, stream>>>(h0b, N, wt + 4 * 65536,
        bq1, bk1, bv1, bs1,
        qb, kvb, kvb + 256, rb,
        256, 512, 512, 256,
        0, 1, 1, 0);
    attn_kernel<64, false, false><<<agrid, 512, 0, stream>>>(
        qb, kvb, rb, Wb1, g1, b1, row_start, csr_src, nullptr, h1f, N, 0.0625f);

    pool_partial_kernel<<<dim3(16, 16), 256, 0, stream>>>(h1f, gstart, partial);
    pool_final_kernel<<<16, 256, 0, stream>>>(partial, gcount, (float*)d_out);
}

// Round 7
// 237.513 us; speedup vs baseline: 1.1602x; 1.1602x over previous
//
#include <hip/hip_runtime.h>
#include <hip/hip_bf16.h>

// ---------------------------------------------------------------------------
// R6 = R5 with the fp8 epilogue write-out bug fixed:
//   R5 wrote only 32 of 64 fp8 bytes per thread (i2<2) leaving poison in
//   K/V cols 32..63 of each half -> absmax 1.95. Now i2<4 covers all 64B.
// R5 structure retained: LDS-staged GEMM epilogue (no byte-store RMW),
// 1D grid + bijective XCD swizzle, fp8 KV attention, two-stage pool.
// ---------------------------------------------------------------------------

#define DEVFN static __device__ __forceinline__

typedef __attribute__((ext_vector_type(4))) float f32x4;
typedef __attribute__((ext_vector_type(2))) float f32x2;
typedef __attribute__((ext_vector_type(8))) short bf16x8;

DEVFN float bfu2f(unsigned short u) {
    union { unsigned int i; float f; } t; t.i = ((unsigned)u) << 16; return t.f;
}
DEVFN float4 ldb4(const __hip_bfloat16* p) {
    ushort4 u = *reinterpret_cast<const ushort4*>(p);
    return make_float4(bfu2f(u.x), bfu2f(u.y), bfu2f(u.z), bfu2f(u.w));
}
DEVFN unsigned short f2bu(float f) {
    __hip_bfloat16 b = __float2bfloat16(f);
    return __builtin_bit_cast(unsigned short, b);
}
DEVFN void stb4(__hip_bfloat16* p, float4 v) {
    ushort4 u;
    u.x = f2bu(v.x); u.y = f2bu(v.y); u.z = f2bu(v.z); u.w = f2bu(v.w);
    *reinterpret_cast<ushort4*>(p) = u;
}
DEVFN float4 f8x4_to_f4(unsigned u) {
    const f32x2 lo = __builtin_amdgcn_cvt_pk_f32_fp8((int)u, false);
    const f32x2 hi = __builtin_amdgcn_cvt_pk_f32_fp8((int)u, true);
    return make_float4(lo.x, lo.y, hi.x, hi.y);
}

// --------------------------- converts ---------------------------------------
__global__ __launch_bounds__(256)
void f2b_kernel(const float* __restrict__ in, __hip_bfloat16* __restrict__ out, int n4)
{
    const int i = blockIdx.x * 256 + threadIdx.x;
    if (i >= n4) return;
    const float4 v = *reinterpret_cast<const float4*>(in + (size_t)i * 4);
    stb4(out + (size_t)i * 4, v);
}

// transpose+convert weights: W[k][c] f32 -> Wt[z][c][k] bf16
__global__ __launch_bounds__(256)
void wconv_kernel(const float* __restrict__ W0, const float* __restrict__ W1,
                  const float* __restrict__ W2, const float* __restrict__ W3,
                  const float* __restrict__ W4, const float* __restrict__ W5,
                  const float* __restrict__ W6, const float* __restrict__ W7,
                  __hip_bfloat16* __restrict__ Wt)
{
    const float* W;
    switch (blockIdx.y) {
        case 0: W = W0; break; case 1: W = W1; break;
        case 2: W = W2; break; case 3: W = W3; break;
        case 4: W = W4; break; case 5: W = W5; break;
        case 6: W = W6; break; default: W = W7; break;
    }
    const int k = blockIdx.x;      // 0..255
    const int c = threadIdx.x;     // 0..255
    Wt[(size_t)blockIdx.y * 65536 + (size_t)c * 256 + k] =
        __float2bfloat16(W[(size_t)k * 256 + c]);
}

// ------------------------- GEMM: O[z] = A @ W[z] + b[z] ---------------------
// 1D grid nrb*8 (rem: colblk 0..1, z 0..3), XCD-swizzled so each XCD owns a
// contiguous band of row-panels (A becomes L2-resident per XCD).
// LDS-staged epilogue: bf16 tile stride 272B; fp8 packed on read-back.
#define SWZ(r, kb) ((r) * 256 + ((kb) ^ (((r) & 7) << 4)))
#define TSTRIDE 272

__global__ __launch_bounds__(256)
void gemm_mfma_kernel(const __hip_bfloat16* __restrict__ A, int M,
                      const __hip_bfloat16* __restrict__ Wt,
                      const float* __restrict__ b0, const float* __restrict__ b1,
                      const float* __restrict__ b2, const float* __restrict__ b3,
                      void* __restrict__ O0, void* __restrict__ O1,
                      void* __restrict__ O2, void* __restrict__ O3,
                      int s0, int s1, int s2, int s3,
                      int f0, int f1, int f2, int f3)
{
    // bijective XCD swizzle (gridDim.x % 8 == 0 here)
    const int q8   = gridDim.x >> 3;
    const int wgid = (blockIdx.x & 7) * q8 + (blockIdx.x >> 3);
    const int rowblk = wgid >> 3;
    const int rem    = wgid & 7;
    const int colblk = rem >> 2;
    const int z      = rem & 3;

    const float* bias; void* O; int rs, isf8;
    switch (z) {
        case 0:  bias = b0; O = O0; rs = s0; isf8 = f0; break;
        case 1:  bias = b1; O = O1; rs = s1; isf8 = f1; break;
        case 2:  bias = b2; O = O2; rs = s2; isf8 = f2; break;
        default: bias = b3; O = O3; rs = s3; isf8 = f3; break;
    }
    const __hip_bfloat16* Wz = Wt + (size_t)z * 65536;

    __shared__ char Sh[2 * 128 * 256];     // As | Bs, reused as epilogue stage
    char* As = Sh;
    char* Bs = Sh + 128 * 256;

    const int tid  = threadIdx.x;
    const int row0 = rowblk * 128;
    const int col0 = colblk * 128;
    const int wid  = tid >> 6, lane = tid & 63;
    const int wr   = wid >> 1, wc = wid & 1;
    const int lrow = lane & 15, kg = lane >> 4;

    const int chunk = tid & 15;
    const int rsub  = tid >> 4;

    f32x4 acc[4][4] = {};

    for (int k0 = 0; k0 < 256; k0 += 128) {
        #pragma unroll
        for (int p = 0; p < 8; ++p) {
            const int r  = p * 16 + rsub;
            const int gr = row0 + r;
            ulonglong2 av = {0ull, 0ull};
            if (gr < M)
                av = *reinterpret_cast<const ulonglong2*>(A + (size_t)gr * 256 + k0 + chunk * 8);
            *reinterpret_cast<ulonglong2*>(As + SWZ(r, chunk * 16)) = av;

            const ulonglong2 bv = *reinterpret_cast<const ulonglong2*>(
                Wz + (size_t)(col0 + r) * 256 + k0 + chunk * 8);
            *reinterpret_cast<ulonglong2*>(Bs + SWZ(r, chunk * 16)) = bv;
        }
        __syncthreads();

        #pragma unroll
        for (int kk = 0; kk < 128; kk += 32) {
            const int kbyte = kk * 2 + kg * 16;
            bf16x8 af[4], bfr[4];
            #pragma unroll
            for (int m = 0; m < 4; ++m) {
                const int r = wr * 64 + m * 16 + lrow;
                af[m] = *reinterpret_cast<const bf16x8*>(As + SWZ(r, kbyte));
            }
            #pragma unroll
            for (int n = 0; n < 4; ++n) {
                const int c = wc * 64 + n * 16 + lrow;
                bfr[n] = *reinterpret_cast<const bf16x8*>(Bs + SWZ(c, kbyte));
            }
            #pragma unroll
            for (int m = 0; m < 4; ++m)
                #pragma unroll
                for (int n = 0; n < 4; ++n)
                    acc[m][n] = __builtin_amdgcn_mfma_f32_16x16x32_bf16(
                        af[m], bfr[n], acc[m][n], 0, 0, 0);
        }
        __syncthreads();
    }

    // ---- epilogue: stage bf16 tile in LDS (stride 272B, 16B-aligned rows) ----
    #pragma unroll
    for (int m = 0; m < 4; ++m) {
        #pragma unroll
        for (int j = 0; j < 4; ++j) {
            const int rr = wr * 64 + m * 16 + kg * 4 + j;
            #pragma unroll
            for (int n = 0; n < 4; ++n) {
                const int cc = wc * 64 + n * 16 + lrow;
                const float v = acc[m][n][j] + bias[col0 + cc];
                *reinterpret_cast<unsigned short*>(Sh + rr * TSTRIDE + cc * 2) = f2bu(v);
            }
        }
    }
    __syncthreads();

    // ---- coalesced write-out: 2 threads per row, 64 cols each ----
    const int row  = tid >> 1;
    const int half = tid & 1;
    const int grow = row0 + row;
    if (grow >= M) return;
    const char* src = Sh + row * TSTRIDE + half * 128;

    if (isf8) {
        // 64 cols -> 64 fp8 bytes -> 4 x uint4 (16B) stores
        unsigned char* dst = (unsigned char*)O + (size_t)grow * rs + col0 + half * 64;
        #pragma unroll
        for (int i2 = 0; i2 < 4; ++i2) {
            uint4 w;
            unsigned tmp[4];
            #pragma unroll
            for (int c8 = 0; c8 < 2; ++c8) {
                const bf16x8 e = *reinterpret_cast<const bf16x8*>(src + (i2 * 2 + c8) * 16);
                const int p0 = __builtin_amdgcn_cvt_pk_fp8_f32(
                    bfu2f((unsigned short)e[0]), bfu2f((unsigned short)e[1]), 0, false);
                const int p1 = __builtin_amdgcn_cvt_pk_fp8_f32(
                    bfu2f((unsigned short)e[2]), bfu2f((unsigned short)e[3]), 0, false);
                const int p2 = __builtin_amdgcn_cvt_pk_fp8_f32(
                    bfu2f((unsigned short)e[4]), bfu2f((unsigned short)e[5]), 0, false);
                const int p3 = __builtin_amdgcn_cvt_pk_fp8_f32(
                    bfu2f((unsigned short)e[6]), bfu2f((unsigned short)e[7]), 0, false);
                tmp[c8 * 2 + 0] = (unsigned)(p0 & 0xFFFF) | ((unsigned)(p1 & 0xFFFF) << 16);
                tmp[c8 * 2 + 1] = (unsigned)(p2 & 0xFFFF) | ((unsigned)(p3 & 0xFFFF) << 16);
            }
            w.x = tmp[0]; w.y = tmp[1]; w.z = tmp[2]; w.w = tmp[3];
            *reinterpret_cast<uint4*>(dst + i2 * 16) = w;
        }
    } else {
        // 64 cols -> 128B bf16 -> 8 x 16B stores
        char* dst = (char*)((__hip_bfloat16*)O + (size_t)grow * rs + col0 + half * 64);
        #pragma unroll
        for (int i = 0; i < 8; ++i)
            *reinterpret_cast<ulonglong2*>(dst + i * 16) =
                *reinterpret_cast<const ulonglong2*>(src + i * 16);
    }
}

// ------------------------------ CSR build ----------------------------------
__global__ __launch_bounds__(256)
void hist_kernel(const int* __restrict__ ei, int E, int* __restrict__ deg)
{
    const int e = blockIdx.x * 256 + threadIdx.x;
    if (e < E) atomicAdd(&deg[ei[E + e]], 1);
}

__global__ __launch_bounds__(256)
void gcount_kernel(const int* __restrict__ batch, int N, int* __restrict__ gcount)
{
    __shared__ int h[16];
    if (threadIdx.x < 16) h[threadIdx.x] = 0;
    __syncthreads();
    const int n = blockIdx.x * 256 + threadIdx.x;
    if (n < N) atomicAdd(&h[batch[n]], 1);
    __syncthreads();
    if (threadIdx.x < 16 && h[threadIdx.x] != 0)
        atomicAdd(&gcount[threadIdx.x], h[threadIdx.x]);
}

__global__ __launch_bounds__(64)
void gstart_kernel(const int* __restrict__ gcount, int* __restrict__ gstart)
{
    if (threadIdx.x == 0) {
        int o = 0;
        for (int g = 0; g < 16; ++g) { gstart[g] = o; o += gcount[g]; }
        gstart[16] = o;
    }
}

__global__ __launch_bounds__(1024)
void scan_kernel(const int* __restrict__ deg, int* __restrict__ row_start, int n)
{
    __shared__ int wsum[16];
    __shared__ int wincl[16];
    const int tid  = threadIdx.x;
    const int w    = tid >> 6;
    const int lane = tid & 63;
    if (tid == 0) row_start[0] = 0;
    int offset = 0;
    for (int base = 0; base < n; base += 1024) {
        const int idx = base + tid;
        int s = (idx < n) ? deg[idx] : 0;
        #pragma unroll
        for (int d = 1; d < 64; d <<= 1) {
            const int t = __shfl_up(s, d, 64);
            if (lane >= d) s += t;
        }
        if (lane == 63) wsum[w] = s;
        __syncthreads();
        if (tid < 16) {
            int si = wsum[tid];
            #pragma unroll
            for (int d = 1; d < 16; d <<= 1) {
                const int u = __shfl_up(si, d, 64);
                if (tid >= d) si += u;
            }
            wincl[tid] = si;
        }
        __syncthreads();
        const int woff = (w > 0) ? wincl[w - 1] : 0;
        if (idx < n) row_start[idx + 1] = offset + woff + s;
        offset += wincl[15];
        __syncthreads();
    }
}

__global__ __launch_bounds__(256)
void fill_kernel(const int* __restrict__ ei, int E,
                 const int* __restrict__ row_start,
                 int* __restrict__ cursor, int* __restrict__ csr_src)
{
    const int e = blockIdx.x * 256 + threadIdx.x;
    if (e >= E) return;
    const int s = ei[e];
    const int d = ei[E + e];
    const int pos = atomicAdd(&cursor[d], 1);
    csr_src[row_start[d] + pos] = s;
}

// --------------------- fused attention + gate + layernorm ------------------
// 512 threads = 8 waves = 4 nodes x 2 waves; 2-deep unroll = 4 gather chains
// per node. KV is fp8 [N][512] bytes (K | V). Decode via v_cvt_pk_f32_fp8.
template <int HL, bool RELU, bool OUTB>
__global__ __launch_bounds__(512)
void attn_kernel(const __hip_bfloat16* __restrict__ Q,
                 const unsigned char* __restrict__ KV,
                 const __hip_bfloat16* __restrict__ R,
                 const float* __restrict__ Wb, const float* __restrict__ lng,
                 const float* __restrict__ lnb,
                 const int* __restrict__ row_start, const int* __restrict__ csr_src,
                 __hip_bfloat16* __restrict__ outb, float* __restrict__ outf,
                 int N, float scale)
{
    __shared__ float4 sAcc[4][64];
    __shared__ float  sSum[4][64];

    const int w    = threadIdx.x >> 6;     // 0..7
    const int lane = threadIdx.x & 63;
    const int slot = w >> 1;               // 0..3
    const int half = w & 1;
    const int node = blockIdx.x * 4 + slot;
    const bool active = node < N;

    const int d4 = lane * 4;
    float4 q4 = make_float4(0.f, 0.f, 0.f, 0.f);
    int beg = 0, end = 0;
    if (active) {
        q4  = ldb4(Q + (size_t)node * 256 + d4);
        beg = row_start[node];
        end = row_start[node + 1];
    }

    float4 acc0 = make_float4(0.f, 0.f, 0.f, 0.f);
    float4 acc1 = make_float4(0.f, 0.f, 0.f, 0.f);
    float  ssum0 = 0.f, ssum1 = 0.f;

    int i = beg + half;
    for (; i + 2 < end; i += 4) {
        const int sa = csr_src[i];
        const int sb = csr_src[i + 2];
        const unsigned* pa = reinterpret_cast<const unsigned*>(KV + (size_t)sa * 512 + d4);
        const unsigned* pb = reinterpret_cast<const unsigned*>(KV + (size_t)sb * 512 + d4);
        const unsigned kua = pa[0];
        const unsigned vua = pa[64];
        const unsigned kub = pb[0];
        const unsigned vub = pb[64];
        const float4 ka = f8x4_to_f4(kua);
        const float4 va = f8x4_to_f4(vua);
        const float4 kb = f8x4_to_f4(kub);
        const float4 vb = f8x4_to_f4(vub);
        float pa_ = q4.x * ka.x + q4.y * ka.y + q4.z * ka.z + q4.w * ka.w;
        float pb_ = q4.x * kb.x + q4.y * kb.y + q4.z * kb.z + q4.w * kb.w;
        #pragma unroll
        for (int m = 1; m < HL; m <<= 1) {
            pa_ += __shfl_xor(pa_, m, 64);
            pb_ += __shfl_xor(pb_, m, 64);
        }
        const float aa = __expf(pa_ * scale);
        const float ab = __expf(pb_ * scale);
        ssum0 += aa; ssum1 += ab;
        acc0.x = fmaf(aa, va.x, acc0.x); acc0.y = fmaf(aa, va.y, acc0.y);
        acc0.z = fmaf(aa, va.z, acc0.z); acc0.w = fmaf(aa, va.w, acc0.w);
        acc1.x = fmaf(ab, vb.x, acc1.x); acc1.y = fmaf(ab, vb.y, acc1.y);
        acc1.z = fmaf(ab, vb.z, acc1.z); acc1.w = fmaf(ab, vb.w, acc1.w);
    }
    if (i < end) {
        const int sa = csr_src[i];
        const unsigned* pa = reinterpret_cast<const unsigned*>(KV + (size_t)sa * 512 + d4);
        const unsigned kua = pa[0];
        const unsigned vua = pa[64];
        const float4 ka = f8x4_to_f4(kua);
        const float4 va = f8x4_to_f4(vua);
        float pa_ = q4.x * ka.x + q4.y * ka.y + q4.z * ka.z + q4.w * ka.w;
        #pragma unroll
        for (int m = 1; m < HL; m <<= 1) pa_ += __shfl_xor(pa_, m, 64);
        const float aa = __expf(pa_ * scale);
        ssum0 += aa;
        acc0.x = fmaf(aa, va.x, acc0.x); acc0.y = fmaf(aa, va.y, acc0.y);
        acc0.z = fmaf(aa, va.z, acc0.z); acc0.w = fmaf(aa, va.w, acc0.w);
    }

    float4 acc = make_float4(acc0.x + acc1.x, acc0.y + acc1.y,
                             acc0.z + acc1.z, acc0.w + acc1.w);
    float ssum = ssum0 + ssum1;

    if (half == 1) {
        sAcc[slot][lane] = acc;
        sSum[slot][lane] = ssum;
    }
    __syncthreads();
    if (half == 1 || !active) return;

    const float4 oa = sAcc[slot][lane];
    acc.x += oa.x; acc.y += oa.y; acc.z += oa.z; acc.w += oa.w;
    ssum += sSum[slot][lane];

    float4 o4 = make_float4(0.f, 0.f, 0.f, 0.f);
    if (ssum > 0.f) {
        const float is = 1.f / ssum;
        o4.x = acc.x * is; o4.y = acc.y * is; o4.z = acc.z * is; o4.w = acc.w * is;
    }

    const float4 r4  = ldb4(R + (size_t)node * 256 + d4);
    const float4 wb0 = *reinterpret_cast<const float4*>(Wb + d4);
    const float4 wb1 = *reinterpret_cast<const float4*>(Wb + 256 + d4);
    const float4 wb2 = *reinterpret_cast<const float4*>(Wb + 512 + d4);
    float z = o4.x * wb0.x + o4.y * wb0.y + o4.z * wb0.z + o4.w * wb0.w
            + r4.x * wb1.x + r4.y * wb1.y + r4.z * wb1.z + r4.w * wb1.w
            + (o4.x - r4.x) * wb2.x + (o4.y - r4.y) * wb2.y
            + (o4.z - r4.z) * wb2.z + (o4.w - r4.w) * wb2.w;
    #pragma unroll
    for (int m = 1; m < 64; m <<= 1) z += __shfl_xor(z, m, 64);
    const float g = 1.f / (1.f + __expf(-z));

    float4 h4;
    h4.x = g * r4.x + (1.f - g) * o4.x;
    h4.y = g * r4.y + (1.f - g) * o4.y;
    h4.z = g * r4.z + (1.f - g) * o4.z;
    h4.w = g * r4.w + (1.f - g) * o4.w;

    float s1 = h4.x + h4.y + h4.z + h4.w;
    float s2 = h4.x * h4.x + h4.y * h4.y + h4.z * h4.z + h4.w * h4.w;
    #pragma unroll
    for (int m = 1; m < 64; m <<= 1) {
        s1 += __shfl_xor(s1, m, 64);
        s2 += __shfl_xor(s2, m, 64);
    }
    const float mu  = s1 * (1.f / 256.f);
    const float var = s2 * (1.f / 256.f) - mu * mu;
    const float inv = rsqrtf(var + 1e-5f);

    const float4 ga = *reinterpret_cast<const float4*>(lng + d4);
    const float4 be = *reinterpret_cast<const float4*>(lnb + d4);
    h4.x = (h4.x - mu) * inv * ga.x + be.x;
    h4.y = (h4.y - mu) * inv * ga.y + be.y;
    h4.z = (h4.z - mu) * inv * ga.z + be.z;
    h4.w = (h4.w - mu) * inv * ga.w + be.w;

    if (RELU) {
        h4.x = fmaxf(h4.x, 0.f);
        h4.y = fmaxf(h4.y, 0.f);
        h4.z = fmaxf(h4.z, 0.f);
        h4.w = fmaxf(h4.w, 0.f);
    }

    if (OUTB) stb4(outb + (size_t)node * 256 + d4, h4);
    else      *reinterpret_cast<float4*>(outf + (size_t)node * 256 + d4) = h4;
}

// ------------------------------ mean pool (two-stage) ----------------------
__global__ __launch_bounds__(256)
void pool_partial_kernel(const float* __restrict__ h, const int* __restrict__ gstart,
                         float* __restrict__ partial)
{
    const int s    = blockIdx.x;
    const int g    = blockIdx.y;
    const int tid  = threadIdx.x;
    const int quad = tid & 63;
    const int sub  = tid >> 6;

    const int beg = gstart[g];
    const int cnt = gstart[g + 1] - beg;

    f32x4 acc = {0.f, 0.f, 0.f, 0.f};
    for (int i = s * 4 + sub; i < cnt; i += 64) {
        const f32x4 v = *reinterpret_cast<const f32x4*>(
            h + (size_t)(beg + i) * 256 + quad * 4);
        acc += v;
    }

    __shared__ f32x4 sh[4][64];
    sh[sub][quad] = acc;
    __syncthreads();
    if (sub == 0) {
        const f32x4 r = sh[0][quad] + sh[1][quad] + sh[2][quad] + sh[3][quad];
        *reinterpret_cast<f32x4*>(partial + ((size_t)(g * 16 + s) * 64 + quad) * 4) = r;
    }
}

__global__ __launch_bounds__(256)
void pool_final_kernel(const float* __restrict__ partial, const int* __restrict__ gcount,
                       float* __restrict__ out)
{
    const int g = blockIdx.x;
    const int d = threadIdx.x;
    float sum = 0.f;
    #pragma unroll
    for (int s = 0; s < 16; ++s)
        sum += partial[(size_t)(g * 16 + s) * 256 + d];
    out[(size_t)g * 256 + d] = sum / (float)max(gcount[g], 1);
}

// ------------------------------- launcher ----------------------------------
extern "C" void kernel_launch(void* const* d_in, const int* in_sizes, int n_in,
                              void* d_out, int out_size, void* d_ws, size_t ws_size,
                              hipStream_t stream)
{
    const float* x     = (const float*)d_in[0];
    const int*   ei    = (const int*)d_in[1];
    const int*   batch = (const int*)d_in[2];
    const float* Wq0 = (const float*)d_in[3];  const float* bq0 = (const float*)d_in[4];
    const float* Wk0 = (const float*)d_in[5];  const float* bk0 = (const float*)d_in[6];
    const float* Wv0 = (const float*)d_in[7];  const float* bv0 = (const float*)d_in[8];
    const float* Ws0 = (const float*)d_in[9];  const float* bs0 = (const float*)d_in[10];
    const float* Wb0 = (const float*)d_in[11];
    const float* g0  = (const float*)d_in[12]; const float* b0  = (const float*)d_in[13];
    const float* Wq1 = (const float*)d_in[14]; const float* bq1 = (const float*)d_in[15];
    const float* Wk1 = (const float*)d_in[16]; const float* bk1 = (const float*)d_in[17];
    const float* Wv1 = (const float*)d_in[18]; const float* bv1 = (const float*)d_in[19];
    const float* Ws1 = (const float*)d_in[20]; const float* bs1 = (const float*)d_in[21];
    const float* Wb1 = (const float*)d_in[22];
    const float* g1  = (const float*)d_in[23]; const float* b1  = (const float*)d_in[24];

    const int N = in_sizes[0] / 256;
    const int E = in_sizes[1] / 2;
    const int G = 16;
    const size_t NM = (size_t)N * 256;

    __hip_bfloat16* bws = (__hip_bfloat16*)d_ws;
    __hip_bfloat16* xb  = bws;
    __hip_bfloat16* qb  = xb  + NM;
    __hip_bfloat16* rb  = qb  + NM;
    __hip_bfloat16* h0b = rb  + NM;
    __hip_bfloat16* wt  = h0b + NM;               // 8 * 65536 bf16
    unsigned char* kvb  = (unsigned char*)(wt + 8 * 65536);   // [N][512] fp8
    float* h1f     = (float*)(kvb + (size_t)N * 512);
    float* partial = h1f + NM;                    // 16*16*256 f32
    int* deg       = (int*)(partial + 16 * 16 * 256);
    int* row_start = deg + N;
    int* cursor    = row_start + N + 1;
    int* gcount    = cursor + N;
    int* gstart    = gcount + G;                  // 17
    int* csr_src   = gstart + 17;

    const size_t zbytes = ((size_t)N + (N + 1) + N + G + 17) * sizeof(int);
    hipMemsetAsync(deg, 0, zbytes, stream);

    const int eb = (E + 255) / 256;
    const int nb = (N + 255) / 256;

    f2b_kernel<<<(int)((NM / 4 + 255) / 256), 256, 0, stream>>>(x, xb, (int)(NM / 4));
    wconv_kernel<<<dim3(256, 8), 256, 0, stream>>>(Wq0, Wk0, Wv0, Ws0,
                                                   Wq1, Wk1, Wv1, Ws1, wt);

    hist_kernel<<<eb, 256, 0, stream>>>(ei, E, deg);
    gcount_kernel<<<nb, 256, 0, stream>>>(batch, N, gcount);
    gstart_kernel<<<1, 64, 0, stream>>>(gcount, gstart);
    scan_kernel<<<1, 1024, 0, stream>>>(deg, row_start, N);
    fill_kernel<<<eb, 256, 0, stream>>>(ei, E, row_start, cursor, csr_src);

    const int nrb   = (N + 127) / 128;
    const int ggrid = nrb * 8;                    // 1D, XCD-swizzled in-kernel
    const int agrid = (N + 3) / 4;

    // layer 0: q bf16, K fp8 (kv+0), V fp8 (kv+256), r bf16
    gemm_mfma_kernel<<<ggrid, 256, 0, stream>>>(xb, N, wt,
        bq0, bk0, bv0, bs0,
        qb, kvb, kvb + 256, rb,
        256, 512, 512, 256,
        0, 1, 1, 0);
    attn_kernel<16, true, true><<<agrid, 512, 0, stream>>>(
        qb, kvb, rb, Wb0, g0, b0, row_start, csr_src, h0b, nullptr, N, 0.125f);

    // layer 1
    gemm_mfma_kernel<<<ggrid, 256, 0, stream>>>(h0b, N, wt + 4 * 65536,
        bq1, bk1, bv1, bs1,
        qb, kvb, kvb + 256, rb,
        256, 512, 512, 256,
        0, 1, 1, 0);
    attn_kernel<64, false, false><<<agrid, 512, 0, stream>>>(
        qb, kvb, rb, Wb1, g1, b1, row_start, csr_src, nullptr, h1f, N, 0.0625f);

    pool_partial_kernel<<<dim3(16, 16), 256, 0, stream>>>(h1f, gstart, partial);
    pool_final_kernel<<<16, 256, 0, stream>>>(partial, gcount, (float*)d_out);
}

// Round 8
// 235.309 us; speedup vs baseline: 1.1711x; 1.0094x over previous
//
#include <hip/hip_runtime.h>
#include <hip/hip_bf16.h>

// ---------------------------------------------------------------------------
// R7: attention restructured into 16-lane edge-groups.
//   R6 evidence: attn VALUBusy 52%, BW 2.0TB/s -> instruction-bound.
//   Now: lane owns 16 dims (16B fp8); wave = 1 node processing 4 edges
//   concurrently (one per 16-lane group); head-reduce shuffles serve 4
//   edges/instr; VMEM instrs per edge 2->0.5; no cross-wave barrier.
// GEMM (LDS epilogue + XCD swizzle), fp8 KV, pool, CSR unchanged from R6.
// ---------------------------------------------------------------------------

#define DEVFN static __device__ __forceinline__

typedef __attribute__((ext_vector_type(4))) float f32x4;
typedef __attribute__((ext_vector_type(2))) float f32x2;
typedef __attribute__((ext_vector_type(8))) short bf16x8;

DEVFN float bfu2f(unsigned short u) {
    union { unsigned int i; float f; } t; t.i = ((unsigned)u) << 16; return t.f;
}
DEVFN float4 ldb4(const __hip_bfloat16* p) {
    ushort4 u = *reinterpret_cast<const ushort4*>(p);
    return make_float4(bfu2f(u.x), bfu2f(u.y), bfu2f(u.z), bfu2f(u.w));
}
DEVFN unsigned short f2bu(float f) {
    __hip_bfloat16 b = __float2bfloat16(f);
    return __builtin_bit_cast(unsigned short, b);
}
DEVFN void stb4(__hip_bfloat16* p, float4 v) {
    ushort4 u;
    u.x = f2bu(v.x); u.y = f2bu(v.y); u.z = f2bu(v.z); u.w = f2bu(v.w);
    *reinterpret_cast<ushort4*>(p) = u;
}
DEVFN float4 f8x4_to_f4(unsigned u) {
    const f32x2 lo = __builtin_amdgcn_cvt_pk_f32_fp8((int)u, false);
    const f32x2 hi = __builtin_amdgcn_cvt_pk_f32_fp8((int)u, true);
    return make_float4(lo.x, lo.y, hi.x, hi.y);
}

// dot of q[16] with 16 fp8 values packed in uint4
DEVFN float dot16(const float* q, uint4 u) {
    const float4 f0 = f8x4_to_f4(u.x);
    const float4 f1 = f8x4_to_f4(u.y);
    const float4 f2 = f8x4_to_f4(u.z);
    const float4 f3 = f8x4_to_f4(u.w);
    float p;
    p = q[0] * f0.x;            p = fmaf(q[1],  f0.y, p);
    p = fmaf(q[2],  f0.z, p);   p = fmaf(q[3],  f0.w, p);
    p = fmaf(q[4],  f1.x, p);   p = fmaf(q[5],  f1.y, p);
    p = fmaf(q[6],  f1.z, p);   p = fmaf(q[7],  f1.w, p);
    p = fmaf(q[8],  f2.x, p);   p = fmaf(q[9],  f2.y, p);
    p = fmaf(q[10], f2.z, p);   p = fmaf(q[11], f2.w, p);
    p = fmaf(q[12], f3.x, p);   p = fmaf(q[13], f3.y, p);
    p = fmaf(q[14], f3.z, p);   p = fmaf(q[15], f3.w, p);
    return p;
}
// acc[16] += a * decode(u)
DEVFN void accum16(float* acc, uint4 u, float a) {
    const float4 f0 = f8x4_to_f4(u.x);
    const float4 f1 = f8x4_to_f4(u.y);
    const float4 f2 = f8x4_to_f4(u.z);
    const float4 f3 = f8x4_to_f4(u.w);
    acc[0]  = fmaf(a, f0.x, acc[0]);  acc[1]  = fmaf(a, f0.y, acc[1]);
    acc[2]  = fmaf(a, f0.z, acc[2]);  acc[3]  = fmaf(a, f0.w, acc[3]);
    acc[4]  = fmaf(a, f1.x, acc[4]);  acc[5]  = fmaf(a, f1.y, acc[5]);
    acc[6]  = fmaf(a, f1.z, acc[6]);  acc[7]  = fmaf(a, f1.w, acc[7]);
    acc[8]  = fmaf(a, f2.x, acc[8]);  acc[9]  = fmaf(a, f2.y, acc[9]);
    acc[10] = fmaf(a, f2.z, acc[10]); acc[11] = fmaf(a, f2.w, acc[11]);
    acc[12] = fmaf(a, f3.x, acc[12]); acc[13] = fmaf(a, f3.y, acc[13]);
    acc[14] = fmaf(a, f3.z, acc[14]); acc[15] = fmaf(a, f3.w, acc[15]);
}

// --------------------------- converts ---------------------------------------
__global__ __launch_bounds__(256)
void f2b_kernel(const float* __restrict__ in, __hip_bfloat16* __restrict__ out, int n4)
{
    const int i = blockIdx.x * 256 + threadIdx.x;
    if (i >= n4) return;
    const float4 v = *reinterpret_cast<const float4*>(in + (size_t)i * 4);
    stb4(out + (size_t)i * 4, v);
}

// transpose+convert weights: W[k][c] f32 -> Wt[z][c][k] bf16
__global__ __launch_bounds__(256)
void wconv_kernel(const float* __restrict__ W0, const float* __restrict__ W1,
                  const float* __restrict__ W2, const float* __restrict__ W3,
                  const float* __restrict__ W4, const float* __restrict__ W5,
                  const float* __restrict__ W6, const float* __restrict__ W7,
                  __hip_bfloat16* __restrict__ Wt)
{
    const float* W;
    switch (blockIdx.y) {
        case 0: W = W0; break; case 1: W = W1; break;
        case 2: W = W2; break; case 3: W = W3; break;
        case 4: W = W4; break; case 5: W = W5; break;
        case 6: W = W6; break; default: W = W7; break;
    }
    const int k = blockIdx.x;      // 0..255
    const int c = threadIdx.x;     // 0..255
    Wt[(size_t)blockIdx.y * 65536 + (size_t)c * 256 + k] =
        __float2bfloat16(W[(size_t)k * 256 + c]);
}

// ------------------------- GEMM: O[z] = A @ W[z] + b[z] ---------------------
#define SWZ(r, kb) ((r) * 256 + ((kb) ^ (((r) & 7) << 4)))
#define TSTRIDE 272

__global__ __launch_bounds__(256)
void gemm_mfma_kernel(const __hip_bfloat16* __restrict__ A, int M,
                      const __hip_bfloat16* __restrict__ Wt,
                      const float* __restrict__ b0, const float* __restrict__ b1,
                      const float* __restrict__ b2, const float* __restrict__ b3,
                      void* __restrict__ O0, void* __restrict__ O1,
                      void* __restrict__ O2, void* __restrict__ O3,
                      int s0, int s1, int s2, int s3,
                      int f0, int f1, int f2, int f3)
{
    // bijective XCD swizzle (gridDim.x % 8 == 0 here)
    const int q8   = gridDim.x >> 3;
    const int wgid = (blockIdx.x & 7) * q8 + (blockIdx.x >> 3);
    const int rowblk = wgid >> 3;
    const int rem    = wgid & 7;
    const int colblk = rem >> 2;
    const int z      = rem & 3;

    const float* bias; void* O; int rs, isf8;
    switch (z) {
        case 0:  bias = b0; O = O0; rs = s0; isf8 = f0; break;
        case 1:  bias = b1; O = O1; rs = s1; isf8 = f1; break;
        case 2:  bias = b2; O = O2; rs = s2; isf8 = f2; break;
        default: bias = b3; O = O3; rs = s3; isf8 = f3; break;
    }
    const __hip_bfloat16* Wz = Wt + (size_t)z * 65536;

    __shared__ char Sh[2 * 128 * 256];     // As | Bs, reused as epilogue stage
    char* As = Sh;
    char* Bs = Sh + 128 * 256;

    const int tid  = threadIdx.x;
    const int row0 = rowblk * 128;
    const int col0 = colblk * 128;
    const int wid  = tid >> 6, lane = tid & 63;
    const int wr   = wid >> 1, wc = wid & 1;
    const int lrow = lane & 15, kg = lane >> 4;

    const int chunk = tid & 15;
    const int rsub  = tid >> 4;

    f32x4 acc[4][4] = {};

    for (int k0 = 0; k0 < 256; k0 += 128) {
        #pragma unroll
        for (int p = 0; p < 8; ++p) {
            const int r  = p * 16 + rsub;
            const int gr = row0 + r;
            ulonglong2 av = {0ull, 0ull};
            if (gr < M)
                av = *reinterpret_cast<const ulonglong2*>(A + (size_t)gr * 256 + k0 + chunk * 8);
            *reinterpret_cast<ulonglong2*>(As + SWZ(r, chunk * 16)) = av;

            const ulonglong2 bv = *reinterpret_cast<const ulonglong2*>(
                Wz + (size_t)(col0 + r) * 256 + k0 + chunk * 8);
            *reinterpret_cast<ulonglong2*>(Bs + SWZ(r, chunk * 16)) = bv;
        }
        __syncthreads();

        #pragma unroll
        for (int kk = 0; kk < 128; kk += 32) {
            const int kbyte = kk * 2 + kg * 16;
            bf16x8 af[4], bfr[4];
            #pragma unroll
            for (int m = 0; m < 4; ++m) {
                const int r = wr * 64 + m * 16 + lrow;
                af[m] = *reinterpret_cast<const bf16x8*>(As + SWZ(r, kbyte));
            }
            #pragma unroll
            for (int n = 0; n < 4; ++n) {
                const int c = wc * 64 + n * 16 + lrow;
                bfr[n] = *reinterpret_cast<const bf16x8*>(Bs + SWZ(c, kbyte));
            }
            #pragma unroll
            for (int m = 0; m < 4; ++m)
                #pragma unroll
                for (int n = 0; n < 4; ++n)
                    acc[m][n] = __builtin_amdgcn_mfma_f32_16x16x32_bf16(
                        af[m], bfr[n], acc[m][n], 0, 0, 0);
        }
        __syncthreads();
    }

    // ---- epilogue: stage bf16 tile in LDS (stride 272B, 16B-aligned rows) ----
    #pragma unroll
    for (int m = 0; m < 4; ++m) {
        #pragma unroll
        for (int j = 0; j < 4; ++j) {
            const int rr = wr * 64 + m * 16 + kg * 4 + j;
            #pragma unroll
            for (int n = 0; n < 4; ++n) {
                const int cc = wc * 64 + n * 16 + lrow;
                const float v = acc[m][n][j] + bias[col0 + cc];
                *reinterpret_cast<unsigned short*>(Sh + rr * TSTRIDE + cc * 2) = f2bu(v);
            }
        }
    }
    __syncthreads();

    // ---- coalesced write-out: 2 threads per row, 64 cols each ----
    const int row  = tid >> 1;
    const int half = tid & 1;
    const int grow = row0 + row;
    if (grow >= M) return;
    const char* src = Sh + row * TSTRIDE + half * 128;

    if (isf8) {
        // 64 cols -> 64 fp8 bytes -> 4 x uint4 (16B) stores
        unsigned char* dst = (unsigned char*)O + (size_t)grow * rs + col0 + half * 64;
        #pragma unroll
        for (int i2 = 0; i2 < 4; ++i2) {
            uint4 w;
            unsigned tmp[4];
            #pragma unroll
            for (int c8 = 0; c8 < 2; ++c8) {
                const bf16x8 e = *reinterpret_cast<const bf16x8*>(src + (i2 * 2 + c8) * 16);
                const int p0 = __builtin_amdgcn_cvt_pk_fp8_f32(
                    bfu2f((unsigned short)e[0]), bfu2f((unsigned short)e[1]), 0, false);
                const int p1 = __builtin_amdgcn_cvt_pk_fp8_f32(
                    bfu2f((unsigned short)e[2]), bfu2f((unsigned short)e[3]), 0, false);
                const int p2 = __builtin_amdgcn_cvt_pk_fp8_f32(
                    bfu2f((unsigned short)e[4]), bfu2f((unsigned short)e[5]), 0, false);
                const int p3 = __builtin_amdgcn_cvt_pk_fp8_f32(
                    bfu2f((unsigned short)e[6]), bfu2f((unsigned short)e[7]), 0, false);
                tmp[c8 * 2 + 0] = (unsigned)(p0 & 0xFFFF) | ((unsigned)(p1 & 0xFFFF) << 16);
                tmp[c8 * 2 + 1] = (unsigned)(p2 & 0xFFFF) | ((unsigned)(p3 & 0xFFFF) << 16);
            }
            w.x = tmp[0]; w.y = tmp[1]; w.z = tmp[2]; w.w = tmp[3];
            *reinterpret_cast<uint4*>(dst + i2 * 16) = w;
        }
    } else {
        // 64 cols -> 128B bf16 -> 8 x 16B stores
        char* dst = (char*)((__hip_bfloat16*)O + (size_t)grow * rs + col0 + half * 64);
        #pragma unroll
        for (int i = 0; i < 8; ++i)
            *reinterpret_cast<ulonglong2*>(dst + i * 16) =
                *reinterpret_cast<const ulonglong2*>(src + i * 16);
    }
}

// ------------------------------ CSR build ----------------------------------
__global__ __launch_bounds__(256)
void hist_kernel(const int* __restrict__ ei, int E, int* __restrict__ deg)
{
    const int e = blockIdx.x * 256 + threadIdx.x;
    if (e < E) atomicAdd(&deg[ei[E + e]], 1);
}

__global__ __launch_bounds__(256)
void gcount_kernel(const int* __restrict__ batch, int N, int* __restrict__ gcount)
{
    __shared__ int h[16];
    if (threadIdx.x < 16) h[threadIdx.x] = 0;
    __syncthreads();
    const int n = blockIdx.x * 256 + threadIdx.x;
    if (n < N) atomicAdd(&h[batch[n]], 1);
    __syncthreads();
    if (threadIdx.x < 16 && h[threadIdx.x] != 0)
        atomicAdd(&gcount[threadIdx.x], h[threadIdx.x]);
}

__global__ __launch_bounds__(64)
void gstart_kernel(const int* __restrict__ gcount, int* __restrict__ gstart)
{
    if (threadIdx.x == 0) {
        int o = 0;
        for (int g = 0; g < 16; ++g) { gstart[g] = o; o += gcount[g]; }
        gstart[16] = o;
    }
}

__global__ __launch_bounds__(1024)
void scan_kernel(const int* __restrict__ deg, int* __restrict__ row_start, int n)
{
    __shared__ int wsum[16];
    __shared__ int wincl[16];
    const int tid  = threadIdx.x;
    const int w    = tid >> 6;
    const int lane = tid & 63;
    if (tid == 0) row_start[0] = 0;
    int offset = 0;
    for (int base = 0; base < n; base += 1024) {
        const int idx = base + tid;
        int s = (idx < n) ? deg[idx] : 0;
        #pragma unroll
        for (int d = 1; d < 64; d <<= 1) {
            const int t = __shfl_up(s, d, 64);
            if (lane >= d) s += t;
        }
        if (lane == 63) wsum[w] = s;
        __syncthreads();
        if (tid < 16) {
            int si = wsum[tid];
            #pragma unroll
            for (int d = 1; d < 16; d <<= 1) {
                const int u = __shfl_up(si, d, 64);
                if (tid >= d) si += u;
            }
            wincl[tid] = si;
        }
        __syncthreads();
        const int woff = (w > 0) ? wincl[w - 1] : 0;
        if (idx < n) row_start[idx + 1] = offset + woff + s;
        offset += wincl[15];
        __syncthreads();
    }
}

__global__ __launch_bounds__(256)
void fill_kernel(const int* __restrict__ ei, int E,
                 const int* __restrict__ row_start,
                 int* __restrict__ cursor, int* __restrict__ csr_src)
{
    const int e = blockIdx.x * 256 + threadIdx.x;
    if (e >= E) return;
    const int s = ei[e];
    const int d = ei[E + e];
    const int pos = atomicAdd(&cursor[d], 1);
    csr_src[row_start[d] + pos] = s;
}

// --------------------- fused attention + gate + layernorm ------------------
// One wave per node. Lane = (group g = lane>>4, sublane s = lane&15).
// Lane owns dims 16s..16s+15 (16B fp8). Group g processes edges beg+g, +4...
// NSH: head-reduce shuffle steps (2 for H=4/C=64, 4 for H=1/C=256).
template <int NSH, bool RELU, bool OUTB>
__global__ __launch_bounds__(256)
void attn_kernel(const __hip_bfloat16* __restrict__ Q,
                 const unsigned char* __restrict__ KV,
                 const __hip_bfloat16* __restrict__ R,
                 const float* __restrict__ Wb, const float* __restrict__ lng,
                 const float* __restrict__ lnb,
                 const int* __restrict__ row_start, const int* __restrict__ csr_src,
                 __hip_bfloat16* __restrict__ outb, float* __restrict__ outf,
                 int N, float scale)
{
    const int wv   = threadIdx.x >> 6;
    const int lane = threadIdx.x & 63;
    const int g    = lane >> 4;
    const int s    = lane & 15;
    const int node = blockIdx.x * 4 + wv;
    if (node >= N) return;

    // q dims 16s..16s+15 (bf16 -> f32)
    float q[16];
    {
        const bf16x8 a = *reinterpret_cast<const bf16x8*>(Q + (size_t)node * 256 + s * 16);
        const bf16x8 b = *reinterpret_cast<const bf16x8*>(Q + (size_t)node * 256 + s * 16 + 8);
        #pragma unroll
        for (int j = 0; j < 8; ++j) {
            q[j]     = bfu2f((unsigned short)a[j]);
            q[8 + j] = bfu2f((unsigned short)b[j]);
        }
    }

    const int beg = row_start[node];
    const int end = row_start[node + 1];

    float acc[16] = {};
    float ssum = 0.f;

    int i = beg + g;
    for (; i + 4 < end; i += 8) {           // 2-deep unroll: edges i, i+4
        const int sa = csr_src[i];
        const int sb = csr_src[i + 4];
        const uint4 ka = *reinterpret_cast<const uint4*>(KV + (size_t)sa * 512 + s * 16);
        const uint4 va = *reinterpret_cast<const uint4*>(KV + (size_t)sa * 512 + 256 + s * 16);
        const uint4 kb = *reinterpret_cast<const uint4*>(KV + (size_t)sb * 512 + s * 16);
        const uint4 vb = *reinterpret_cast<const uint4*>(KV + (size_t)sb * 512 + 256 + s * 16);
        float pa = dot16(q, ka);
        float pb = dot16(q, kb);
        #pragma unroll
        for (int m = 1; m < (1 << NSH); m <<= 1) {
            pa += __shfl_xor(pa, m, 64);
            pb += __shfl_xor(pb, m, 64);
        }
        const float aa = __expf(pa * scale);
        const float ab = __expf(pb * scale);
        ssum += aa + ab;
        accum16(acc, va, aa);
        accum16(acc, vb, ab);
    }
    if (i < end) {
        const int sa = csr_src[i];
        const uint4 ka = *reinterpret_cast<const uint4*>(KV + (size_t)sa * 512 + s * 16);
        const uint4 va = *reinterpret_cast<const uint4*>(KV + (size_t)sa * 512 + 256 + s * 16);
        float pa = dot16(q, ka);
        #pragma unroll
        for (int m = 1; m < (1 << NSH); m <<= 1) pa += __shfl_xor(pa, m, 64);
        const float aa = __expf(pa * scale);
        ssum += aa;
        accum16(acc, va, aa);
    }

    // cross-group combine (groups differ, sublane preserved by masks 16/32)
    ssum += __shfl_xor(ssum, 16, 64);
    ssum += __shfl_xor(ssum, 32, 64);
    #pragma unroll
    for (int j = 0; j < 16; ++j) {
        acc[j] += __shfl_xor(acc[j], 16, 64);
        acc[j] += __shfl_xor(acc[j], 32, 64);
    }

    if (g != 0) return;    // epilogue on group 0 only (holds all 256 dims)

    const float is = (ssum > 0.f) ? 1.f / ssum : 0.f;
    float o[16];
    #pragma unroll
    for (int j = 0; j < 16; ++j) o[j] = acc[j] * is;

    float r[16];
    {
        const bf16x8 a = *reinterpret_cast<const bf16x8*>(R + (size_t)node * 256 + s * 16);
        const bf16x8 b = *reinterpret_cast<const bf16x8*>(R + (size_t)node * 256 + s * 16 + 8);
        #pragma unroll
        for (int j = 0; j < 8; ++j) {
            r[j]     = bfu2f((unsigned short)a[j]);
            r[8 + j] = bfu2f((unsigned short)b[j]);
        }
    }

    // beta gate: z = [o, r, o-r] . Wb  (full 256-dim dot via 16-sublane reduce)
    float z = 0.f;
    #pragma unroll
    for (int j = 0; j < 16; ++j) {
        const int d = s * 16 + j;
        z += o[j] * Wb[d] + r[j] * Wb[256 + d] + (o[j] - r[j]) * Wb[512 + d];
    }
    #pragma unroll
    for (int m = 1; m < 16; m <<= 1) z += __shfl_xor(z, m, 64);
    const float gg = 1.f / (1.f + __expf(-z));

    float h[16];
    float s1 = 0.f, s2 = 0.f;
    #pragma unroll
    for (int j = 0; j < 16; ++j) {
        h[j] = gg * r[j] + (1.f - gg) * o[j];
        s1 += h[j];
        s2 += h[j] * h[j];
    }
    #pragma unroll
    for (int m = 1; m < 16; m <<= 1) {
        s1 += __shfl_xor(s1, m, 64);
        s2 += __shfl_xor(s2, m, 64);
    }
    const float mu  = s1 * (1.f / 256.f);
    const float var = s2 * (1.f / 256.f) - mu * mu;
    const float inv = rsqrtf(var + 1e-5f);

    #pragma unroll
    for (int j = 0; j < 16; ++j) {
        const int d = s * 16 + j;
        h[j] = (h[j] - mu) * inv * lng[d] + lnb[d];
        if (RELU) h[j] = fmaxf(h[j], 0.f);
    }

    if (OUTB) {
        __hip_bfloat16* dst = outb + (size_t)node * 256 + s * 16;
        stb4(dst,      make_float4(h[0],  h[1],  h[2],  h[3]));
        stb4(dst + 4,  make_float4(h[4],  h[5],  h[6],  h[7]));
        stb4(dst + 8,  make_float4(h[8],  h[9],  h[10], h[11]));
        stb4(dst + 12, make_float4(h[12], h[13], h[14], h[15]));
    } else {
        float* dst = outf + (size_t)node * 256 + s * 16;
        #pragma unroll
        for (int c4 = 0; c4 < 4; ++c4)
            *reinterpret_cast<float4*>(dst + c4 * 4) =
                make_float4(h[c4 * 4], h[c4 * 4 + 1], h[c4 * 4 + 2], h[c4 * 4 + 3]);
    }
}

// ------------------------------ mean pool (two-stage) ----------------------
__global__ __launch_bounds__(256)
void pool_partial_kernel(const float* __restrict__ h, const int* __restrict__ gstart,
                         float* __restrict__ partial)
{
    const int s    = blockIdx.x;
    const int g    = blockIdx.y;
    const int tid  = threadIdx.x;
    const int quad = tid & 63;
    const int sub  = tid >> 6;

    const int beg = gstart[g];
    const int cnt = gstart[g + 1] - beg;

    f32x4 acc = {0.f, 0.f, 0.f, 0.f};
    for (int i = s * 4 + sub; i < cnt; i += 64) {
        const f32x4 v = *reinterpret_cast<const f32x4*>(
            h + (size_t)(beg + i) * 256 + quad * 4);
        acc += v;
    }

    __shared__ f32x4 sh[4][64];
    sh[sub][quad] = acc;
    __syncthreads();
    if (sub == 0) {
        const f32x4 r = sh[0][quad] + sh[1][quad] + sh[2][quad] + sh[3][quad];
        *reinterpret_cast<f32x4*>(partial + ((size_t)(g * 16 + s) * 64 + quad) * 4) = r;
    }
}

__global__ __launch_bounds__(256)
void pool_final_kernel(const float* __restrict__ partial, const int* __restrict__ gcount,
                       float* __restrict__ out)
{
    const int g = blockIdx.x;
    const int d = threadIdx.x;
    float sum = 0.f;
    #pragma unroll
    for (int s = 0; s < 16; ++s)
        sum += partial[(size_t)(g * 16 + s) * 256 + d];
    out[(size_t)g * 256 + d] = sum / (float)max(gcount[g], 1);
}

// ------------------------------- launcher ----------------------------------
extern "C" void kernel_launch(void* const* d_in, const int* in_sizes, int n_in,
                              void* d_out, int out_size, void* d_ws, size_t ws_size,
                              hipStream_t stream)
{
    const float* x     = (const float*)d_in[0];
    const int*   ei    = (const int*)d_in[1];
    const int*   batch = (const int*)d_in[2];
    const float* Wq0 = (const float*)d_in[3];  const float* bq0 = (const float*)d_in[4];
    const float* Wk0 = (const float*)d_in[5];  const float* bk0 = (const float*)d_in[6];
    const float* Wv0 = (const float*)d_in[7];  const float* bv0 = (const float*)d_in[8];
    const float* Ws0 = (const float*)d_in[9];  const float* bs0 = (const float*)d_in[10];
    const float* Wb0 = (const float*)d_in[11];
    const float* g0  = (const float*)d_in[12]; const float* b0  = (const float*)d_in[13];
    const float* Wq1 = (const float*)d_in[14]; const float* bq1 = (const float*)d_in[15];
    const float* Wk1 = (const float*)d_in[16]; const float* bk1 = (const float*)d_in[17];
    const float* Wv1 = (const float*)d_in[18]; const float* bv1 = (const float*)d_in[19];
    const float* Ws1 = (const float*)d_in[20]; const float* bs1 = (const float*)d_in[21];
    const float* Wb1 = (const float*)d_in[22];
    const float* g1  = (const float*)d_in[23]; const float* b1  = (const float*)d_in[24];

    const int N = in_sizes[0] / 256;
    const int E = in_sizes[1] / 2;
    const int G = 16;
    const size_t NM = (size_t)N * 256;

    __hip_bfloat16* bws = (__hip_bfloat16*)d_ws;
    __hip_bfloat16* xb  = bws;
    __hip_bfloat16* qb  = xb  + NM;
    __hip_bfloat16* rb  = qb  + NM;
    __hip_bfloat16* h0b = rb  + NM;
    __hip_bfloat16* wt  = h0b + NM;               // 8 * 65536 bf16
    unsigned char* kvb  = (unsigned char*)(wt + 8 * 65536);   // [N][512] fp8
    float* h1f     = (float*)(kvb + (size_t)N * 512);
    float* partial = h1f + NM;                    // 16*16*256 f32
    int* deg       = (int*)(partial + 16 * 16 * 256);
    int* row_start = deg + N;
    int* cursor    = row_start + N + 1;
    int* gcount    = cursor + N;
    int* gstart    = gcount + G;                  // 17
    int* csr_src   = gstart + 17;

    const size_t zbytes = ((size_t)N + (N + 1) + N + G + 17) * sizeof(int);
    hipMemsetAsync(deg, 0, zbytes, stream);

    const int eb = (E + 255) / 256;
    const int nb = (N + 255) / 256;

    f2b_kernel<<<(int)((NM / 4 + 255) / 256), 256, 0, stream>>>(x, xb, (int)(NM / 4));
    wconv_kernel<<<dim3(256, 8), 256, 0, stream>>>(Wq0, Wk0, Wv0, Ws0,
                                                   Wq1, Wk1, Wv1, Ws1, wt);

    hist_kernel<<<eb, 256, 0, stream>>>(ei, E, deg);
    gcount_kernel<<<nb, 256, 0, stream>>>(batch, N, gcount);
    gstart_kernel<<<1, 64, 0, stream>>>(gcount, gstart);
    scan_kernel<<<1, 1024, 0, stream>>>(deg, row_start, N);
    fill_kernel<<<eb, 256, 0, stream>>>(ei, E, row_start, cursor, csr_src);

    const int nrb   = (N + 127) / 128;
    const int ggrid = nrb * 8;                    // 1D, XCD-swizzled in-kernel
    const int agrid = (N + 3) / 4;

    // layer 0: q bf16, K fp8 (kv+0), V fp8 (kv+256), r bf16
    gemm_mfma_kernel<<<ggrid, 256, 0, stream>>>(xb, N, wt,
        bq0, bk0, bv0, bs0,
        qb, kvb, kvb + 256, rb,
        256, 512, 512, 256,
        0, 1, 1, 0);
    attn_kernel<2, true, true><<<agrid, 256, 0, stream>>>(
        qb, kvb, rb, Wb0, g0, b0, row_start, csr_src, h0b, nullptr, N, 0.125f);

    // layer 1
    gemm_mfma_kernel<<<ggrid, 256, 0, stream>>>(h0b, N, wt + 4 * 65536,
        bq1, bk1, bv1, bs1,
        qb, kvb, kvb + 256, rb,
        256, 512, 512, 256,
        0, 1, 1, 0);
    attn_kernel<4, false, false><<<agrid, 256, 0, stream>>>(
        qb, kvb, rb, Wb1, g1, b1, row_start, csr_src, nullptr, h1f, N, 0.0625f);

    pool_partial_kernel<<<dim3(16, 16), 256, 0, stream>>>(h1f, gstart, partial);
    pool_final_kernel<<<16, 256, 0, stream>>>(partial, gcount, (float*)d_out);
}